// Round 1
// baseline (5868.324 us; speedup 1.0000x reference)
//
#include <hip/hip_runtime.h>

// LSTM_76622216560744: 2-layer LSTM (H=50), B=2048, T=1024, input dim 1.
// Strategy: grid=256 blocks (1/CU), block=256 threads, 8 batch elements/block.
// Weights in per-thread registers (thread t<200 owns gate row t); h-state in
// LDS read via wave-broadcast; c-state in updating thread's registers.

#define TT 1024
#define HH 50
#define GG 200      // 4*H gates
#define BS 8        // batch per block
#define NT 256      // threads per block
#define HROW 104    // h12s row stride: h1[0:50], h2[50:100], pad to 16B mult

__device__ __forceinline__ float fast_rcp(float x) { return __builtin_amdgcn_rcpf(x); }
__device__ __forceinline__ float sigm(float x) { return fast_rcp(1.0f + __expf(-x)); }
__device__ __forceinline__ float ftanh(float x) {
    float e = __expf(-2.0f * x);
    return (1.0f - e) * fast_rcp(1.0f + e);
}

__global__ __launch_bounds__(NT, 1) void lstm_kernel(
    const float* __restrict__ x,
    const float* __restrict__ W_ih1, const float* __restrict__ W_hh1,
    const float* __restrict__ b_ih1, const float* __restrict__ b_hh1,
    const float* __restrict__ W_ih2, const float* __restrict__ W_hh2,
    const float* __restrict__ b_ih2, const float* __restrict__ b_hh2,
    const float* __restrict__ W_lin, const float* __restrict__ b_lin,
    float* __restrict__ out)
{
    __shared__ float xs[BS * TT];        // 32 KB staged input slice
    __shared__ float h12s[BS * HROW];    // h1|h2 per batch, 16B-aligned rows
    __shared__ float gs[BS * GG];        // gate exchange buffer

    const int tid = threadIdx.x;
    const int b0g = blockIdx.x * BS;

    // Stage this block's x rows (fully coalesced: linear copy of 8 rows).
    for (int i = tid; i < BS * TT; i += NT) xs[i] = x[b0g * TT + i];
    for (int i = tid; i < BS * HROW; i += NT) h12s[i] = 0.0f;

    // Per-thread persistent weights: thread t<200 owns gate row t.
    float w1[52];   // W_hh1 row (k=50,51 zero-padded; reads into h2[0:2] are x0)
    float w2[100];  // [W_ih2 | W_hh2] row, multiplies [h1;h2]
    float wx = 0.f, bias1t = 0.f, bias2t = 0.f;
    if (tid < GG) {
        wx = W_ih1[tid];
        bias1t = b_ih1[tid] + b_hh1[tid];
        bias2t = b_ih2[tid] + b_hh2[tid];
        #pragma unroll
        for (int k = 0; k < HH; ++k) w1[k] = W_hh1[tid * HH + k];
        w1[50] = 0.f; w1[51] = 0.f;
        #pragma unroll
        for (int k = 0; k < HH; ++k) w2[k] = W_ih2[tid * HH + k];
        #pragma unroll
        for (int k = 0; k < HH; ++k) w2[50 + k] = W_hh2[tid * HH + k];
    }

    // Cell-state registers: thread t<200 with q=t/50, u=t%50 updates unit u of
    // batches 2q and 2q+1 every step (fixed mapping -> c stays in registers).
    const int q = tid / HH;
    const int u = tid - q * HH;
    const int bu0 = 2 * q;
    float c1r0 = 0.f, c1r1 = 0.f, c2r0 = 0.f, c2r1 = 0.f;

    __syncthreads();

    for (int t = 0; t < TT; ++t) {
        // ---------------- Layer 1 gates: g1 = wx*x_t + bias + Whh1 @ h1 ----
        if (tid < GG) {
            float acc[BS];
            #pragma unroll
            for (int b = 0; b < BS; ++b) acc[b] = bias1t + wx * xs[b * TT + t];
            #pragma unroll
            for (int kc = 0; kc < 52; kc += 4) {
                #pragma unroll
                for (int b = 0; b < BS; ++b) {
                    float4 h4 = *(const float4*)&h12s[b * HROW + kc];
                    acc[b] += w1[kc] * h4.x + w1[kc + 1] * h4.y
                            + w1[kc + 2] * h4.z + w1[kc + 3] * h4.w;
                }
            }
            #pragma unroll
            for (int b = 0; b < BS; ++b) gs[b * GG + tid] = acc[b];
        }
        __syncthreads();
        // ---------------- Layer 1 cell/hidden update ----------------------
        if (tid < GG) {
            #pragma unroll
            for (int j = 0; j < 2; ++j) {
                int b = bu0 + j;
                float gi = gs[b * GG + u];
                float gf = gs[b * GG + u + 50];
                float gc = gs[b * GG + u + 100];
                float go = gs[b * GG + u + 150];
                float cprev = j ? c1r1 : c1r0;
                float cn = sigm(gf) * cprev + sigm(gi) * ftanh(gc);
                if (j) c1r1 = cn; else c1r0 = cn;
                h12s[b * HROW + u] = sigm(go) * ftanh(cn);
            }
        }
        __syncthreads();
        // ---------------- Layer 2 gates: g2 = bias + [Wih2|Whh2]@[h1;h2] ---
        if (tid < GG) {
            float acc[BS];
            #pragma unroll
            for (int b = 0; b < BS; ++b) acc[b] = bias2t;
            #pragma unroll
            for (int kc = 0; kc < 100; kc += 4) {
                #pragma unroll
                for (int b = 0; b < BS; ++b) {
                    float4 h4 = *(const float4*)&h12s[b * HROW + kc];
                    acc[b] += w2[kc] * h4.x + w2[kc + 1] * h4.y
                            + w2[kc + 2] * h4.z + w2[kc + 3] * h4.w;
                }
            }
            #pragma unroll
            for (int b = 0; b < BS; ++b) gs[b * GG + tid] = acc[b];
        }
        __syncthreads();
        // ---------------- Layer 2 cell/hidden update ----------------------
        if (tid < GG) {
            #pragma unroll
            for (int j = 0; j < 2; ++j) {
                int b = bu0 + j;
                float gi = gs[b * GG + u];
                float gf = gs[b * GG + u + 50];
                float gc = gs[b * GG + u + 100];
                float go = gs[b * GG + u + 150];
                float cprev = j ? c2r1 : c2r0;
                float cn = sigm(gf) * cprev + sigm(gi) * ftanh(gc);
                if (j) c2r1 = cn; else c2r0 = cn;
                h12s[b * HROW + 50 + u] = sigm(go) * ftanh(cn);
            }
        }
        __syncthreads();
    }

    // Final linear: out[b] = W_lin . h2_final + b_lin
    if (tid < BS) {
        float s = b_lin[0];
        #pragma unroll
        for (int k = 0; k < HH; ++k) s += W_lin[k] * h12s[tid * HROW + 50 + k];
        out[b0g + tid] = s;
    }
}

extern "C" void kernel_launch(void* const* d_in, const int* in_sizes, int n_in,
                              void* d_out, int out_size, void* d_ws, size_t ws_size,
                              hipStream_t stream) {
    const float* x     = (const float*)d_in[0];
    const float* W_ih1 = (const float*)d_in[1];
    const float* W_hh1 = (const float*)d_in[2];
    const float* b_ih1 = (const float*)d_in[3];
    const float* b_hh1 = (const float*)d_in[4];
    const float* W_ih2 = (const float*)d_in[5];
    const float* W_hh2 = (const float*)d_in[6];
    const float* b_ih2 = (const float*)d_in[7];
    const float* b_hh2 = (const float*)d_in[8];
    const float* W_lin = (const float*)d_in[9];
    const float* b_lin = (const float*)d_in[10];
    float* out = (float*)d_out;

    const int Btot = in_sizes[0] / TT;   // 2048
    const int nblocks = Btot / BS;       // 256

    lstm_kernel<<<nblocks, NT, 0, stream>>>(
        x, W_ih1, W_hh1, b_ih1, b_hh1, W_ih2, W_hh2, b_ih2, b_hh2,
        W_lin, b_lin, out);
}